// Round 5
// baseline (358.834 us; speedup 1.0000x reference)
//
#include <hip/hip_runtime.h>
#include <math.h>

#define B_ROWS 262144

// ws layout (4-byte cells) — total ~123 KB (proven size envelope):
//  A: minmax partials: 128 x 22  (mapped-uint min[10], max[10], cm, cf)
//  B: hist partials:   128 x 200 at offset 2816
//  C: main partials:   3 x 768   at offset 28416
#define WS_A 0
#define WS_B 2816
#define WS_C 28416
#define MAIN_BLOCKS 768     // 3 blocks/CU (LDS 53 KB/block), all resident
#define TILE_ROWS 32
#define N_TILES 8192        // 262144 / 32
#define TILE_F4 792         // 32*99/4 float4 per array per tile

__device__ __forceinline__ unsigned int map_f(float x) {
  unsigned int b = __float_as_uint(x);
  return (b & 0x80000000u) ? ~b : (b | 0x80000000u);
}
__device__ __forceinline__ float unmap_f(unsigned int u) {
  unsigned int b = (u & 0x80000000u) ? (u ^ 0x80000000u) : ~u;
  return __uint_as_float(b);
}

// ---------------- pass 1 over data_encoded ----------------
__global__ __launch_bounds__(256) void k_minmax(const float* __restrict__ enc,
                                                unsigned int* __restrict__ ws) {
  int tid = threadIdx.x, bid = blockIdx.x;
  const float4* e4 = (const float4*)enc;
  float mn[10], mx[10];
  #pragma unroll
  for (int j = 0; j < 10; j++) { mn[j] = 1e30f; mx[j] = -1e30f; }
  unsigned int cm = 0, cf = 0;
  #pragma unroll
  for (int i = 0; i < 8; i++) {
    size_t g = (size_t)bid * 2048 + i * 256 + tid;
    float4 a = e4[g * 3 + 0], b = e4[g * 3 + 1], c = e4[g * 3 + 2];
    float v[12] = {a.x,a.y,a.z,a.w,b.x,b.y,b.z,b.w,c.x,c.y,c.z,c.w};
    #pragma unroll
    for (int j = 0; j < 10; j++) { mn[j] = fminf(mn[j], v[j]); mx[j] = fmaxf(mx[j], v[j]); }
    cm += (v[11] == 0.0f); cf += (v[11] == 1.0f);
  }
  #pragma unroll
  for (int off = 32; off; off >>= 1) {
    #pragma unroll
    for (int j = 0; j < 10; j++) {
      mn[j] = fminf(mn[j], __shfl_xor(mn[j], off));
      mx[j] = fmaxf(mx[j], __shfl_xor(mx[j], off));
    }
    cm += __shfl_xor(cm, off); cf += __shfl_xor(cf, off);
  }
  __shared__ float smn[4][10], smx[4][10];
  __shared__ unsigned int sc[4][2];
  int wave = tid >> 6, lane = tid & 63;
  if (lane == 0) {
    #pragma unroll
    for (int j = 0; j < 10; j++) { smn[wave][j] = mn[j]; smx[wave][j] = mx[j]; }
    sc[wave][0] = cm; sc[wave][1] = cf;
  }
  __syncthreads();
  unsigned int* out = ws + WS_A + bid * 22;
  if (tid < 10) {
    float m = fminf(fminf(smn[0][tid], smn[1][tid]), fminf(smn[2][tid], smn[3][tid]));
    out[tid] = map_f(m);
  } else if (tid < 20) {
    int j = tid - 10;
    float m = fmaxf(fmaxf(smx[0][j], smx[1][j]), fmaxf(smx[2][j], smx[3][j]));
    out[tid] = map_f(m);
  } else if (tid < 22) {
    int j = tid - 20;
    out[tid] = sc[0][j] + sc[1][j] + sc[2][j] + sc[3][j];
  }
}

// ---------------- pass 2 over data_encoded: histograms ----------------
__global__ __launch_bounds__(256) void k_hist(const float* __restrict__ enc,
                                              unsigned int* __restrict__ ws) {
  __shared__ float mnv[10], wid[10];
  __shared__ unsigned int h[200];
  int tid = threadIdx.x, bid = blockIdx.x;
  for (int i = tid; i < 200; i += 256) h[i] = 0u;
  if (tid < 10) {
    unsigned int umn = 0xFFFFFFFFu, umx = 0u;
    #pragma unroll 4
    for (int b = 0; b < 128; b++) {
      umn = min(umn, ws[WS_A + b * 22 + tid]);
      umx = max(umx, ws[WS_A + b * 22 + 10 + tid]);
    }
    float mn = unmap_f(umn);
    mnv[tid] = mn;
    wid[tid] = fmaxf(unmap_f(umx) - mn, 1e-12f);
  }
  __syncthreads();
  const float4* e4 = (const float4*)enc;
  #pragma unroll
  for (int i = 0; i < 8; i++) {
    size_t g = (size_t)bid * 2048 + i * 256 + tid;
    float4 a = e4[g * 3 + 0], b = e4[g * 3 + 1], c = e4[g * 3 + 2];
    float v[12] = {a.x,a.y,a.z,a.w,b.x,b.y,b.z,b.w,c.x,c.y,c.z,c.w};
    int base = (v[11] == 0.0f) ? 0 : ((v[11] == 1.0f) ? 100 : -1);
    if (base >= 0) {
      #pragma unroll
      for (int cc = 0; cc < 10; cc++) {
        float t = (v[cc] - mnv[cc]) / wid[cc] * 10.0f;  // reference op order
        int bi = min(max((int)floorf(t), 0), 9);
        atomicAdd(&h[base + cc * 10 + bi], 1u);
      }
    }
  }
  __syncthreads();
  if (tid < 200) ws[WS_B + bid * 200 + tid] = h[tid];
}

// ---------------- main pass: fine-grained vmcnt software pipeline ----------------
// 1 wave/block, 3 blocks/CU. Tile = 32 rows x 99 cols. BOTH arrays staged
// direct-to-LDS via global_load_lds (no VGPR staging => nothing for the
// compiler to fragment). Two buffers as FOUR distinct __shared__ objects so
// alias analysis doesn't conservatively drain the other buffer's in-flight
// DMAs. Loop: issue next tile's 26 DMAs, THEN s_waitcnt vmcnt(26) — waits
// only for the 26 oldest (current tile), next tile stays in flight under
// the compute. This is the hipBLASLt never-vmcnt(0) pattern, expressible
// here because 1 wave/block makes vmcnt exactly FIFO-countable.
__shared__ float s_d0[3328], s_t0[3328], s_d1[3328], s_t1[3328];

__device__ __forceinline__ void stage_tile(const float4* __restrict__ d4,
                                           const float4* __restrict__ t4,
                                           int tileIdx, float* ldsd, float* ldst,
                                           int lane) {
  const float4* ds = d4 + (size_t)tileIdx * TILE_F4;
  const float4* ts = t4 + (size_t)tileIdx * TILE_F4;
  #pragma unroll
  for (int it = 0; it < 12; ++it)
    __builtin_amdgcn_global_load_lds(
        (const __attribute__((address_space(1))) void*)(ds + it * 64 + lane),
        (__attribute__((address_space(3))) void*)(ldsd + it * 256), 16, 0, 0);
  if (lane < 24)   // 792 = 12*64 + 24: masked tail (still one vmcnt event)
    __builtin_amdgcn_global_load_lds(
        (const __attribute__((address_space(1))) void*)(ds + 768 + lane),
        (__attribute__((address_space(3))) void*)(ldsd + 3072), 16, 0, 0);
  #pragma unroll
  for (int it = 0; it < 12; ++it)
    __builtin_amdgcn_global_load_lds(
        (const __attribute__((address_space(1))) void*)(ts + it * 64 + lane),
        (__attribute__((address_space(3))) void*)(ldst + it * 256), 16, 0, 0);
  if (lane < 24)
    __builtin_amdgcn_global_load_lds(
        (const __attribute__((address_space(1))) void*)(ts + 768 + lane),
        (__attribute__((address_space(3))) void*)(ldst + 3072), 16, 0, 0);
}

__device__ __forceinline__ void compute_tile(const float* ldsd, const float* ldst,
                                             int lane, float& mse, float& dot,
                                             float& ce) {
  // mse/dot from aligned ds_read_b128 of both arrays
  const float4* ld4 = (const float4*)ldsd;
  const float4* lt4 = (const float4*)ldst;
  #pragma unroll
  for (int it = 0; it < 13; ++it) {
    int f = it * 64 + lane;
    if (f < TILE_F4) {
      float4 xd = ld4[f];
      float4 xt = lt4[f];
      int e = f * 4;
      int c = e - (e / 99) * 99;        // magic-mul const divisor
      float dv[4] = {xd.x, xd.y, xd.z, xd.w};
      float tv[4] = {xt.x, xt.y, xt.z, xt.w};
      #pragma unroll
      for (int k = 0; k < 4; k++) {
        int cc = c + k;
        if (cc >= 99) cc -= 99;
        bool cont = (cc == 0) | ((unsigned)(cc - 55) <= 2u);
        float diff = dv[k] - tv[k];
        if (cont) mse += diff * diff;
        else      dot += tv[k] * dv[k];
      }
    }
  }
  // LSE: 2 lanes per row, split at col 51 (a CE-block boundary).
  // LDS banks: addr = r*99+c, bank = (3r+c) mod 32 — distinct over r: conflict-free.
  int r = lane >> 1;
  const float* row = ldsd + r * 99;
  float Z;
  if ((lane & 1) == 0) {               // blocks (1,8)(8,24)(24,31)(31,45)(45,51)
    Z = 0.f;
    #pragma unroll
    for (int c = 1; c < 8; c++) Z += __expf(row[c]);
    ce += __logf(Z);
    Z = 0.f;
    #pragma unroll
    for (int c = 8; c < 24; c++) Z += __expf(row[c]);
    ce += __logf(Z);
    Z = 0.f;
    #pragma unroll
    for (int c = 24; c < 31; c++) Z += __expf(row[c]);
    ce += __logf(Z);
    Z = 0.f;
    #pragma unroll
    for (int c = 31; c < 45; c++) Z += __expf(row[c]);
    ce += __logf(Z);
    Z = 0.f;
    #pragma unroll
    for (int c = 45; c < 51; c++) Z += __expf(row[c]);
    ce += __logf(Z);
  } else {                             // blocks (51,53)(53,55)(58,99)
    Z = 0.f;
    #pragma unroll
    for (int c = 51; c < 53; c++) Z += __expf(row[c]);
    ce += __logf(Z);
    Z = 0.f;
    #pragma unroll
    for (int c = 53; c < 55; c++) Z += __expf(row[c]);
    ce += __logf(Z);
    Z = 0.f;
    #pragma unroll
    for (int c = 58; c < 99; c++) Z += __expf(row[c]);
    ce += __logf(Z);
  }
}

__global__ __launch_bounds__(64) void k_main(const float* __restrict__ d,
                                             const float* __restrict__ t,
                                             unsigned int* __restrict__ ws) {
  int lane = threadIdx.x, bid = blockIdx.x;
  const float4* d4 = (const float4*)d;
  const float4* t4 = (const float4*)t;
  float mse = 0.f, dot = 0.f, ce = 0.f;

  stage_tile(d4, t4, bid, s_d0, s_t0, lane);      // prologue: tile0 -> buf0
  int buf = 0;
  for (int i = bid; i < N_TILES; i += MAIN_BLOCKS) {
    int nxt = i + MAIN_BLOCKS;
    if (nxt < N_TILES) {
      stage_tile(d4, t4, nxt, buf ? s_d0 : s_d1, buf ? s_t0 : s_t1, lane);
      asm volatile("s_waitcnt vmcnt(26)" ::: "memory");  // oldest 26 = tile i
    } else {
      asm volatile("s_waitcnt vmcnt(0)" ::: "memory");
    }
    if (buf) compute_tile(s_d1, s_t1, lane, mse, dot, ce);
    else     compute_tile(s_d0, s_t0, lane, mse, dot, ce);
    asm volatile("" ::: "memory");     // compiler fence: keep ds_reads before
    buf ^= 1;                          // next iteration's DMA re-stage
  }

  #pragma unroll
  for (int off = 32; off; off >>= 1) {
    mse += __shfl_xor(mse, off);
    dot += __shfl_xor(dot, off);
    ce  += __shfl_xor(ce,  off);
  }
  if (lane == 0) {
    float* C = (float*)(ws + WS_C);
    C[bid]                   = mse;
    C[MAIN_BLOCKS + bid]     = dot;
    C[2 * MAIN_BLOCKS + bid] = ce;
  }
}

// ---------------- finalize ----------------
__global__ __launch_bounds__(256) void k_final(const unsigned int* __restrict__ ws,
                                               float* __restrict__ out) {
  __shared__ float h[200];
  __shared__ float part[256];
  __shared__ float red3[12];
  __shared__ float cnts[2];
  int tid = threadIdx.x;
  if (tid < 200) {
    unsigned int s = 0;
    #pragma unroll 4
    for (int b = 0; b < 128; b++) s += ws[WS_B + b * 200 + tid];
    h[tid] = (float)s;
  }
  if (tid == 200 || tid == 201) {
    unsigned int s = 0;
    #pragma unroll 4
    for (int b = 0; b < 128; b++) s += ws[WS_A + b * 22 + 20 + (tid - 200)];
    cnts[tid - 200] = fmaxf((float)s, 1.0f);
  }
  const float* C = (const float*)(ws + WS_C);
  float msum = 0.f, dsum = 0.f, csum = 0.f;
  for (int i = tid; i < MAIN_BLOCKS; i += 256) {
    msum += C[i]; dsum += C[MAIN_BLOCKS + i]; csum += C[2 * MAIN_BLOCKS + i];
  }
  #pragma unroll
  for (int off = 32; off; off >>= 1) {
    msum += __shfl_xor(msum, off);
    dsum += __shfl_xor(dsum, off);
    csum += __shfl_xor(csum, off);
  }
  int wave = tid >> 6, lane = tid & 63;
  if (lane == 0) { red3[wave] = msum; red3[4 + wave] = dsum; red3[8 + wave] = csum; }
  __syncthreads();
  float term = 0.f;
  if (tid < 100) {
    float mc = h[tid], fc = h[100 + tid];
    if (mc > 0.f && fc > 0.f) {
      float p = mc / cnts[0];
      float q = fc / cnts[1];
      term = p * logf(p / q);
    }
  }
  part[tid] = term;
  __syncthreads();
  for (int s = 128; s; s >>= 1) {
    if (tid < s) part[tid] += part[tid + s];
    __syncthreads();
  }
  if (tid == 0) {
    const float invB = 1.0f / (float)B_ROWS;
    float mse = (red3[0] + red3[1] + red3[2] + red3[3]) * invB;
    float dd  = (red3[4] + red3[5] + red3[6] + red3[7]);
    float cc  = (red3[8] + red3[9] + red3[10] + red3[11]);
    float ce  = (cc - dd) * invB;
    float akld = 0.5f * part[0];
    out[0] = 0.5f * (mse + ce) + akld;
    out[1] = mse;
    out[2] = ce;
    out[3] = akld;
  }
}

extern "C" void kernel_launch(void* const* d_in, const int* in_sizes, int n_in,
                              void* d_out, int out_size, void* d_ws, size_t ws_size,
                              hipStream_t stream) {
  const float* enc = (const float*)d_in[0];   // data_encoded (B,12)
  const float* dec = (const float*)d_in[1];   // data_decoded (B,99)
  const float* tru = (const float*)d_in[2];   // data_true    (B,99)
  unsigned int* ws = (unsigned int*)d_ws;
  float* out = (float*)d_out;

  hipLaunchKernelGGL(k_minmax, dim3(128),         dim3(256), 0, stream, enc, ws);
  hipLaunchKernelGGL(k_hist,   dim3(128),         dim3(256), 0, stream, enc, ws);
  hipLaunchKernelGGL(k_main,   dim3(MAIN_BLOCKS), dim3(64),  0, stream, dec, tru, ws);
  hipLaunchKernelGGL(k_final,  dim3(1),           dim3(256), 0, stream, ws, out);
}

// Round 6
// 271.310 us; speedup vs baseline: 1.3226x; 1.3226x over previous
//
#include <hip/hip_runtime.h>
#include <math.h>

#define B_ROWS 262144

// ws layout (4-byte cells):
//  A: minmax partials: 128 x 22  (mapped-uint min[10], max[10], cm, cf)
//  B: hist partials:   128 x 200 at offset 2816
//  C: main partials:   3 x 3072  at offset 28416
#define WS_A 0
#define WS_B 2816
#define WS_C 28416
#define MAIN_BLOCKS 768       // 3 blocks/CU resident (50.7 KB LDS/block)
#define N_WAVES (MAIN_BLOCKS * 4)
#define TILE_ROWS 16
#define N_TILES 16384         // 262144 / 16
#define TILE_F4 396           // 16*99/4 float4 per array per tile

__device__ __forceinline__ unsigned int map_f(float x) {
  unsigned int b = __float_as_uint(x);
  return (b & 0x80000000u) ? ~b : (b | 0x80000000u);
}
__device__ __forceinline__ float unmap_f(unsigned int u) {
  unsigned int b = (u & 0x80000000u) ? (u ^ 0x80000000u) : ~u;
  return __uint_as_float(b);
}

// ---------------- pass 1 over data_encoded ----------------
__global__ __launch_bounds__(256) void k_minmax(const float* __restrict__ enc,
                                                unsigned int* __restrict__ ws) {
  int tid = threadIdx.x, bid = blockIdx.x;
  const float4* e4 = (const float4*)enc;
  float mn[10], mx[10];
  #pragma unroll
  for (int j = 0; j < 10; j++) { mn[j] = 1e30f; mx[j] = -1e30f; }
  unsigned int cm = 0, cf = 0;
  #pragma unroll
  for (int i = 0; i < 8; i++) {
    size_t g = (size_t)bid * 2048 + i * 256 + tid;
    float4 a = e4[g * 3 + 0], b = e4[g * 3 + 1], c = e4[g * 3 + 2];
    float v[12] = {a.x,a.y,a.z,a.w,b.x,b.y,b.z,b.w,c.x,c.y,c.z,c.w};
    #pragma unroll
    for (int j = 0; j < 10; j++) { mn[j] = fminf(mn[j], v[j]); mx[j] = fmaxf(mx[j], v[j]); }
    cm += (v[11] == 0.0f); cf += (v[11] == 1.0f);
  }
  #pragma unroll
  for (int off = 32; off; off >>= 1) {
    #pragma unroll
    for (int j = 0; j < 10; j++) {
      mn[j] = fminf(mn[j], __shfl_xor(mn[j], off));
      mx[j] = fmaxf(mx[j], __shfl_xor(mx[j], off));
    }
    cm += __shfl_xor(cm, off); cf += __shfl_xor(cf, off);
  }
  __shared__ float smn[4][10], smx[4][10];
  __shared__ unsigned int sc[4][2];
  int wave = tid >> 6, lane = tid & 63;
  if (lane == 0) {
    #pragma unroll
    for (int j = 0; j < 10; j++) { smn[wave][j] = mn[j]; smx[wave][j] = mx[j]; }
    sc[wave][0] = cm; sc[wave][1] = cf;
  }
  __syncthreads();
  unsigned int* out = ws + WS_A + bid * 22;
  if (tid < 10) {
    float m = fminf(fminf(smn[0][tid], smn[1][tid]), fminf(smn[2][tid], smn[3][tid]));
    out[tid] = map_f(m);
  } else if (tid < 20) {
    int j = tid - 10;
    float m = fmaxf(fmaxf(smx[0][j], smx[1][j]), fmaxf(smx[2][j], smx[3][j]));
    out[tid] = map_f(m);
  } else if (tid < 22) {
    int j = tid - 20;
    out[tid] = sc[0][j] + sc[1][j] + sc[2][j] + sc[3][j];
  }
}

// ---------------- pass 2 over data_encoded: histograms ----------------
__global__ __launch_bounds__(256) void k_hist(const float* __restrict__ enc,
                                              unsigned int* __restrict__ ws) {
  __shared__ float mnv[10], wid[10];
  __shared__ unsigned int h[200];
  int tid = threadIdx.x, bid = blockIdx.x;
  for (int i = tid; i < 200; i += 256) h[i] = 0u;
  if (tid < 10) {
    unsigned int umn = 0xFFFFFFFFu, umx = 0u;
    #pragma unroll 4
    for (int b = 0; b < 128; b++) {
      umn = min(umn, ws[WS_A + b * 22 + tid]);
      umx = max(umx, ws[WS_A + b * 22 + 10 + tid]);
    }
    float mn = unmap_f(umn);
    mnv[tid] = mn;
    wid[tid] = fmaxf(unmap_f(umx) - mn, 1e-12f);
  }
  __syncthreads();
  const float4* e4 = (const float4*)enc;
  #pragma unroll
  for (int i = 0; i < 8; i++) {
    size_t g = (size_t)bid * 2048 + i * 256 + tid;
    float4 a = e4[g * 3 + 0], b = e4[g * 3 + 1], c = e4[g * 3 + 2];
    float v[12] = {a.x,a.y,a.z,a.w,b.x,b.y,b.z,b.w,c.x,c.y,c.z,c.w};
    int base = (v[11] == 0.0f) ? 0 : ((v[11] == 1.0f) ? 100 : -1);
    if (base >= 0) {
      #pragma unroll
      for (int cc = 0; cc < 10; cc++) {
        float t = (v[cc] - mnv[cc]) / wid[cc] * 10.0f;  // reference op order
        int bi = min(max((int)floorf(t), 0), 9);
        atomicAdd(&h[base + cc * 10 + bi], 1u);
      }
    }
  }
  __syncthreads();
  if (tid < 200) ws[WS_B + bid * 200 + tid] = h[tid];
}

// ---------------- main pass: wave-independent streaming ----------------
// 256-thread blocks, 4 waves, NO __syncthreads in the loop. Each wave owns a
// private 12.4 KB LDS slice (16-row tile x {d,t}) and its own tile stream.
// vmcnt is PER-WAVE state: each wave's drain only waits on its own 14 DMAs
// while the other 11 waves/CU keep their loads in flight — overlap via TLP,
// not intra-wave pipelining (which the compiler defeats; R5 evidence).
// 3 blocks/CU = 12 waves/CU, ~180 KB/CU outstanding on average.
__global__ __launch_bounds__(256) void k_main(const float* __restrict__ d,
                                              const float* __restrict__ t,
                                              unsigned int* __restrict__ ws) {
  __shared__ float sd[4 * 3168];        // 4 waves x (16 rows x 99 cols + 384/4 pad)
  __shared__ float st[4 * 3168];
  int tid = threadIdx.x, bid = blockIdx.x;
  int wave = tid >> 6, lane = tid & 63;
  float* ldsd = sd + wave * 3168;
  float* ldst = st + wave * 3168;
  const float4* ld4 = (const float4*)ldsd;
  const float4* lt4 = (const float4*)ldst;
  int gw = bid * 4 + wave;              // global wave index

  float mse = 0.f, dot = 0.f, ce = 0.f;

  for (int tile = gw; tile < N_TILES; tile += N_WAVES) {
    const float4* ds = (const float4*)d + (size_t)tile * TILE_F4;
    const float4* ts = (const float4*)t + (size_t)tile * TILE_F4;
    // ---- stage both arrays direct-to-LDS: 14 fire-and-forget DMAs ----
    #pragma unroll
    for (int it = 0; it < 6; ++it)
      __builtin_amdgcn_global_load_lds(
          (const __attribute__((address_space(1))) void*)(ds + it * 64 + lane),
          (__attribute__((address_space(3))) void*)(ldsd + it * 1024 / 4), 16, 0, 0);
    if (lane < 12)                      // 396 = 6*64 + 12 tail
      __builtin_amdgcn_global_load_lds(
          (const __attribute__((address_space(1))) void*)(ds + 384 + lane),
          (__attribute__((address_space(3))) void*)(ldsd + 1536), 16, 0, 0);
    #pragma unroll
    for (int it = 0; it < 6; ++it)
      __builtin_amdgcn_global_load_lds(
          (const __attribute__((address_space(1))) void*)(ts + it * 64 + lane),
          (__attribute__((address_space(3))) void*)(ldst + it * 1024 / 4), 16, 0, 0);
    if (lane < 12)
      __builtin_amdgcn_global_load_lds(
          (const __attribute__((address_space(1))) void*)(ts + 384 + lane),
          (__attribute__((address_space(3))) void*)(ldst + 1536), 16, 0, 0);

    // per-wave drain: only THIS wave's 14 loads
    asm volatile("s_waitcnt vmcnt(0)" ::: "memory");

    // ---- mse/dot from aligned b128 LDS reads of both arrays ----
    #pragma unroll
    for (int it = 0; it < 7; ++it) {
      int f = it * 64 + lane;
      if (f < TILE_F4) {
        float4 xd = ld4[f];
        float4 xt = lt4[f];
        int e = f * 4;
        int c = e - (e / 99) * 99;      // magic-mul const divisor
        float dv[4] = {xd.x, xd.y, xd.z, xd.w};
        float tv[4] = {xt.x, xt.y, xt.z, xt.w};
        #pragma unroll
        for (int k = 0; k < 4; k++) {
          int cc = c + k;
          if (cc >= 99) cc -= 99;
          bool cont = (cc == 0) | ((unsigned)(cc - 55) <= 2u);
          float diff = dv[k] - tv[k];
          if (cont) mse += diff * diff;
          else      dot += tv[k] * dv[k];
        }
      }
    }
    // ---- LSE: lanes 0-15, one full row per lane, straight-line ----
    if (lane < TILE_ROWS) {
      const float* row = ldsd + lane * 99;
      float Z;
      Z = 0.f;
      #pragma unroll
      for (int c = 1; c < 8; c++) Z += __expf(row[c]);
      ce += __logf(Z);
      Z = 0.f;
      #pragma unroll
      for (int c = 8; c < 24; c++) Z += __expf(row[c]);
      ce += __logf(Z);
      Z = 0.f;
      #pragma unroll
      for (int c = 24; c < 31; c++) Z += __expf(row[c]);
      ce += __logf(Z);
      Z = 0.f;
      #pragma unroll
      for (int c = 31; c < 45; c++) Z += __expf(row[c]);
      ce += __logf(Z);
      Z = 0.f;
      #pragma unroll
      for (int c = 45; c < 51; c++) Z += __expf(row[c]);
      ce += __logf(Z);
      Z = 0.f;
      #pragma unroll
      for (int c = 51; c < 53; c++) Z += __expf(row[c]);
      ce += __logf(Z);
      Z = 0.f;
      #pragma unroll
      for (int c = 53; c < 55; c++) Z += __expf(row[c]);
      ce += __logf(Z);
      Z = 0.f;
      #pragma unroll
      for (int c = 58; c < 99; c++) Z += __expf(row[c]);
      ce += __logf(Z);
    }
    // all ds_reads of this slice complete before next tile's DMA overwrites it
    asm volatile("s_waitcnt lgkmcnt(0)" ::: "memory");
  }

  // ---- per-wave butterfly reduction, per-wave partial slot ----
  #pragma unroll
  for (int off = 32; off; off >>= 1) {
    mse += __shfl_xor(mse, off);
    dot += __shfl_xor(dot, off);
    ce  += __shfl_xor(ce,  off);
  }
  if (lane == 0) {
    float* C = (float*)(ws + WS_C);
    C[gw]               = mse;
    C[N_WAVES + gw]     = dot;
    C[2 * N_WAVES + gw] = ce;
  }
}

// ---------------- finalize ----------------
__global__ __launch_bounds__(256) void k_final(const unsigned int* __restrict__ ws,
                                               float* __restrict__ out) {
  __shared__ float h[200];
  __shared__ float part[256];
  __shared__ float red3[12];
  __shared__ float cnts[2];
  int tid = threadIdx.x;
  if (tid < 200) {
    unsigned int s = 0;
    #pragma unroll 4
    for (int b = 0; b < 128; b++) s += ws[WS_B + b * 200 + tid];
    h[tid] = (float)s;
  }
  if (tid == 200 || tid == 201) {
    unsigned int s = 0;
    #pragma unroll 4
    for (int b = 0; b < 128; b++) s += ws[WS_A + b * 22 + 20 + (tid - 200)];
    cnts[tid - 200] = fmaxf((float)s, 1.0f);
  }
  const float* C = (const float*)(ws + WS_C);
  float msum = 0.f, dsum = 0.f, csum = 0.f;
  for (int i = tid; i < N_WAVES; i += 256) {
    msum += C[i]; dsum += C[N_WAVES + i]; csum += C[2 * N_WAVES + i];
  }
  #pragma unroll
  for (int off = 32; off; off >>= 1) {
    msum += __shfl_xor(msum, off);
    dsum += __shfl_xor(dsum, off);
    csum += __shfl_xor(csum, off);
  }
  int wave = tid >> 6, lane = tid & 63;
  if (lane == 0) { red3[wave] = msum; red3[4 + wave] = dsum; red3[8 + wave] = csum; }
  __syncthreads();
  float term = 0.f;
  if (tid < 100) {
    float mc = h[tid], fc = h[100 + tid];
    if (mc > 0.f && fc > 0.f) {
      float p = mc / cnts[0];
      float q = fc / cnts[1];
      term = p * logf(p / q);
    }
  }
  part[tid] = term;
  __syncthreads();
  for (int s = 128; s; s >>= 1) {
    if (tid < s) part[tid] += part[tid + s];
    __syncthreads();
  }
  if (tid == 0) {
    const float invB = 1.0f / (float)B_ROWS;
    float mse = (red3[0] + red3[1] + red3[2] + red3[3]) * invB;
    float dd  = (red3[4] + red3[5] + red3[6] + red3[7]);
    float cc  = (red3[8] + red3[9] + red3[10] + red3[11]);
    float ce  = (cc - dd) * invB;
    float akld = 0.5f * part[0];
    out[0] = 0.5f * (mse + ce) + akld;
    out[1] = mse;
    out[2] = ce;
    out[3] = akld;
  }
}

extern "C" void kernel_launch(void* const* d_in, const int* in_sizes, int n_in,
                              void* d_out, int out_size, void* d_ws, size_t ws_size,
                              hipStream_t stream) {
  const float* enc = (const float*)d_in[0];   // data_encoded (B,12)
  const float* dec = (const float*)d_in[1];   // data_decoded (B,99)
  const float* tru = (const float*)d_in[2];   // data_true    (B,99)
  unsigned int* ws = (unsigned int*)d_ws;
  float* out = (float*)d_out;

  hipLaunchKernelGGL(k_minmax, dim3(128),         dim3(256), 0, stream, enc, ws);
  hipLaunchKernelGGL(k_hist,   dim3(128),         dim3(256), 0, stream, enc, ws);
  hipLaunchKernelGGL(k_main,   dim3(MAIN_BLOCKS), dim3(256), 0, stream, dec, tru, ws);
  hipLaunchKernelGGL(k_final,  dim3(1),           dim3(256), 0, stream, ws, out);
}

// Round 7
// 269.980 us; speedup vs baseline: 1.3291x; 1.0049x over previous
//
#include <hip/hip_runtime.h>
#include <math.h>

#define B_ROWS 262144

// ws layout (4-byte cells), total 33024 cells = 132 KB (≤150 KB proven):
//  A: minmax partials: 128 x 22  (mapped-uint min[10], max[10], cm, cf)
//  B: hist partials:   128 x 200 at offset 2816
//  C: main partials:   3 x 1536  at offset 28416
#define WS_A 0
#define WS_B 2816
#define WS_C 28416
#define MAIN_BLOCKS 1536      // 6 blocks/CU resident (12.8 KB LDS, VGPR<=85)
#define N_WAVES (MAIN_BLOCKS * 4)   // 6144 wave streams
#define TILE_ROWS 8
#define N_TILES 32768         // 262144 / 8
#define TILE_F4 198           // 8*99/4 float4 per array per tile

__device__ __forceinline__ unsigned int map_f(float x) {
  unsigned int b = __float_as_uint(x);
  return (b & 0x80000000u) ? ~b : (b | 0x80000000u);
}
__device__ __forceinline__ float unmap_f(unsigned int u) {
  unsigned int b = (u & 0x80000000u) ? (u ^ 0x80000000u) : ~u;
  return __uint_as_float(b);
}

// ---------------- pass 1 over data_encoded ----------------
__global__ __launch_bounds__(256) void k_minmax(const float* __restrict__ enc,
                                                unsigned int* __restrict__ ws) {
  int tid = threadIdx.x, bid = blockIdx.x;
  const float4* e4 = (const float4*)enc;
  float mn[10], mx[10];
  #pragma unroll
  for (int j = 0; j < 10; j++) { mn[j] = 1e30f; mx[j] = -1e30f; }
  unsigned int cm = 0, cf = 0;
  #pragma unroll
  for (int i = 0; i < 8; i++) {
    size_t g = (size_t)bid * 2048 + i * 256 + tid;
    float4 a = e4[g * 3 + 0], b = e4[g * 3 + 1], c = e4[g * 3 + 2];
    float v[12] = {a.x,a.y,a.z,a.w,b.x,b.y,b.z,b.w,c.x,c.y,c.z,c.w};
    #pragma unroll
    for (int j = 0; j < 10; j++) { mn[j] = fminf(mn[j], v[j]); mx[j] = fmaxf(mx[j], v[j]); }
    cm += (v[11] == 0.0f); cf += (v[11] == 1.0f);
  }
  #pragma unroll
  for (int off = 32; off; off >>= 1) {
    #pragma unroll
    for (int j = 0; j < 10; j++) {
      mn[j] = fminf(mn[j], __shfl_xor(mn[j], off));
      mx[j] = fmaxf(mx[j], __shfl_xor(mx[j], off));
    }
    cm += __shfl_xor(cm, off); cf += __shfl_xor(cf, off);
  }
  __shared__ float smn[4][10], smx[4][10];
  __shared__ unsigned int sc[4][2];
  int wave = tid >> 6, lane = tid & 63;
  if (lane == 0) {
    #pragma unroll
    for (int j = 0; j < 10; j++) { smn[wave][j] = mn[j]; smx[wave][j] = mx[j]; }
    sc[wave][0] = cm; sc[wave][1] = cf;
  }
  __syncthreads();
  unsigned int* out = ws + WS_A + bid * 22;
  if (tid < 10) {
    float m = fminf(fminf(smn[0][tid], smn[1][tid]), fminf(smn[2][tid], smn[3][tid]));
    out[tid] = map_f(m);
  } else if (tid < 20) {
    int j = tid - 10;
    float m = fmaxf(fmaxf(smx[0][j], smx[1][j]), fmaxf(smx[2][j], smx[3][j]));
    out[tid] = map_f(m);
  } else if (tid < 22) {
    int j = tid - 20;
    out[tid] = sc[0][j] + sc[1][j] + sc[2][j] + sc[3][j];
  }
}

// ---------------- pass 2 over data_encoded: histograms ----------------
__global__ __launch_bounds__(256) void k_hist(const float* __restrict__ enc,
                                              unsigned int* __restrict__ ws) {
  __shared__ float mnv[10], wid[10];
  __shared__ unsigned int h[200];
  int tid = threadIdx.x, bid = blockIdx.x;
  for (int i = tid; i < 200; i += 256) h[i] = 0u;
  if (tid < 10) {
    unsigned int umn = 0xFFFFFFFFu, umx = 0u;
    #pragma unroll 4
    for (int b = 0; b < 128; b++) {
      umn = min(umn, ws[WS_A + b * 22 + tid]);
      umx = max(umx, ws[WS_A + b * 22 + 10 + tid]);
    }
    float mn = unmap_f(umn);
    mnv[tid] = mn;
    wid[tid] = fmaxf(unmap_f(umx) - mn, 1e-12f);
  }
  __syncthreads();
  const float4* e4 = (const float4*)enc;
  #pragma unroll
  for (int i = 0; i < 8; i++) {
    size_t g = (size_t)bid * 2048 + i * 256 + tid;
    float4 a = e4[g * 3 + 0], b = e4[g * 3 + 1], c = e4[g * 3 + 2];
    float v[12] = {a.x,a.y,a.z,a.w,b.x,b.y,b.z,b.w,c.x,c.y,c.z,c.w};
    int base = (v[11] == 0.0f) ? 0 : ((v[11] == 1.0f) ? 100 : -1);
    if (base >= 0) {
      #pragma unroll
      for (int cc = 0; cc < 10; cc++) {
        float t = (v[cc] - mnv[cc]) / wid[cc] * 10.0f;  // reference op order
        int bi = min(max((int)floorf(t), 0), 9);
        atomicAdd(&h[base + cc * 10 + bi], 1u);
      }
    }
  }
  __syncthreads();
  if (tid < 200) ws[WS_B + bid * 200 + tid] = h[tid];
}

// ---------------- main pass: 24 wave-streams/CU ----------------
// 1536 blocks x 4 waves, all resident (12.8 KB LDS, VGPR capped <=85 by
// __launch_bounds__(256,6)). NO barriers in the loop; each wave owns a
// 3.2 KB d-slice and a private tile stream. t goes through REGISTERS (4
// float4) — its vmcnt wait is the intended drain point and also covers the
// 4 d-DMAs (single per-wave drain; other 23 waves keep flowing). LSE: 2
// lanes/row (even: cols 1-51, odd: 51-99; 44/45 exps, balanced).
__global__ __launch_bounds__(256, 6) void k_main(const float* __restrict__ d,
                                                 const float* __restrict__ t,
                                                 unsigned int* __restrict__ ws) {
  __shared__ float sd[4][800];          // per-wave d slices (8 rows x 99 + pad)
  __shared__ float red[12];
  int tid = threadIdx.x, bid = blockIdx.x;
  int wave = tid >> 6, lane = tid & 63;
  float* ldsd = sd[wave];
  const float4* ld4 = (const float4*)ldsd;
  int gw = bid * 4 + wave;              // global wave stream id

  float mse = 0.f, dot = 0.f, ce = 0.f;

  for (int tile = gw; tile < N_TILES; tile += N_WAVES) {
    const float4* ds = (const float4*)d + (size_t)tile * TILE_F4;
    const float4* ts = (const float4*)t + (size_t)tile * TILE_F4;
    // ---- d -> LDS: 3 full DMAs + masked tail (198 = 3*64 + 6) ----
    #pragma unroll
    for (int it = 0; it < 3; ++it)
      __builtin_amdgcn_global_load_lds(
          (const __attribute__((address_space(1))) void*)(ds + it * 64 + lane),
          (__attribute__((address_space(3))) void*)(ldsd + it * 256), 16, 0, 0);
    if (lane < 6)
      __builtin_amdgcn_global_load_lds(
          (const __attribute__((address_space(1))) void*)(ds + 192 + lane),
          (__attribute__((address_space(3))) void*)(ldsd + 768), 16, 0, 0);
    // ---- t -> regs: 3 full + masked tail; in flight with the DMAs ----
    float4 tv0 = ts[lane];
    float4 tv1 = ts[64 + lane];
    float4 tv2 = ts[128 + lane];
    float4 tv3 = (lane < 6) ? ts[192 + lane] : make_float4(0.f, 0.f, 0.f, 0.f);
    // single per-wave drain: covers the DMAs (FIFO) and the t loads
    asm volatile("s_waitcnt vmcnt(0)" ::: "memory");

    // ---- mse/dot: d from LDS (b128), t from regs ----
    float4 tvv[4] = {tv0, tv1, tv2, tv3};
    #pragma unroll
    for (int it = 0; it < 4; ++it) {
      int f = it * 64 + lane;
      if (f < TILE_F4) {
        float4 xd = ld4[f];
        float4 xt = tvv[it];
        int e = f * 4;
        int c = e - (e / 99) * 99;      // magic-mul const divisor
        float dv[4] = {xd.x, xd.y, xd.z, xd.w};
        float tw[4] = {xt.x, xt.y, xt.z, xt.w};
        #pragma unroll
        for (int k = 0; k < 4; k++) {
          int cc = c + k;
          if (cc >= 99) cc -= 99;
          bool cont = (cc == 0) | ((unsigned)(cc - 55) <= 2u);
          float diff = dv[k] - tw[k];
          if (cont) mse += diff * diff;
          else      dot += tw[k] * dv[k];
        }
      }
    }
    // ---- LSE: 2 lanes/row, split at col 51 (a CE-block boundary) ----
    if (lane < 2 * TILE_ROWS) {
      const float* row = ldsd + (lane >> 1) * 99;
      float Z;
      if ((lane & 1) == 0) {            // blocks (1,8)(8,24)(24,31)(31,45)(45,51)
        Z = 0.f;
        #pragma unroll
        for (int c = 1; c < 8; c++) Z += __expf(row[c]);
        ce += __logf(Z);
        Z = 0.f;
        #pragma unroll
        for (int c = 8; c < 24; c++) Z += __expf(row[c]);
        ce += __logf(Z);
        Z = 0.f;
        #pragma unroll
        for (int c = 24; c < 31; c++) Z += __expf(row[c]);
        ce += __logf(Z);
        Z = 0.f;
        #pragma unroll
        for (int c = 31; c < 45; c++) Z += __expf(row[c]);
        ce += __logf(Z);
        Z = 0.f;
        #pragma unroll
        for (int c = 45; c < 51; c++) Z += __expf(row[c]);
        ce += __logf(Z);
      } else {                          // blocks (51,53)(53,55)(58,99)
        Z = 0.f;
        #pragma unroll
        for (int c = 51; c < 53; c++) Z += __expf(row[c]);
        ce += __logf(Z);
        Z = 0.f;
        #pragma unroll
        for (int c = 53; c < 55; c++) Z += __expf(row[c]);
        ce += __logf(Z);
        Z = 0.f;
        #pragma unroll
        for (int c = 58; c < 99; c++) Z += __expf(row[c]);
        ce += __logf(Z);
      }
    }
    // compiler's lgkmcnt waits on the accumulator uses guarantee all
    // ds_reads completed before next tile's DMAs can land (issued next iter)
  }

  // ---- block reduction (single barrier AFTER the streaming loop) ----
  #pragma unroll
  for (int off = 32; off; off >>= 1) {
    mse += __shfl_xor(mse, off);
    dot += __shfl_xor(dot, off);
    ce  += __shfl_xor(ce,  off);
  }
  if (lane == 0) { red[wave] = mse; red[4 + wave] = dot; red[8 + wave] = ce; }
  __syncthreads();
  if (tid == 0) {
    float* C = (float*)(ws + WS_C);
    C[bid]                   = red[0] + red[1] + red[2]  + red[3];
    C[MAIN_BLOCKS + bid]     = red[4] + red[5] + red[6]  + red[7];
    C[2 * MAIN_BLOCKS + bid] = red[8] + red[9] + red[10] + red[11];
  }
}

// ---------------- finalize ----------------
__global__ __launch_bounds__(256) void k_final(const unsigned int* __restrict__ ws,
                                               float* __restrict__ out) {
  __shared__ float h[200];
  __shared__ float part[256];
  __shared__ float red3[12];
  __shared__ float cnts[2];
  int tid = threadIdx.x;
  if (tid < 200) {
    unsigned int s = 0;
    #pragma unroll 4
    for (int b = 0; b < 128; b++) s += ws[WS_B + b * 200 + tid];
    h[tid] = (float)s;
  }
  if (tid == 200 || tid == 201) {
    unsigned int s = 0;
    #pragma unroll 4
    for (int b = 0; b < 128; b++) s += ws[WS_A + b * 22 + 20 + (tid - 200)];
    cnts[tid - 200] = fmaxf((float)s, 1.0f);
  }
  const float* C = (const float*)(ws + WS_C);
  float msum = 0.f, dsum = 0.f, csum = 0.f;
  for (int i = tid; i < MAIN_BLOCKS; i += 256) {
    msum += C[i]; dsum += C[MAIN_BLOCKS + i]; csum += C[2 * MAIN_BLOCKS + i];
  }
  #pragma unroll
  for (int off = 32; off; off >>= 1) {
    msum += __shfl_xor(msum, off);
    dsum += __shfl_xor(dsum, off);
    csum += __shfl_xor(csum, off);
  }
  int wave = tid >> 6, lane = tid & 63;
  if (lane == 0) { red3[wave] = msum; red3[4 + wave] = dsum; red3[8 + wave] = csum; }
  __syncthreads();
  float term = 0.f;
  if (tid < 100) {
    float mc = h[tid], fc = h[100 + tid];
    if (mc > 0.f && fc > 0.f) {
      float p = mc / cnts[0];
      float q = fc / cnts[1];
      term = p * logf(p / q);
    }
  }
  part[tid] = term;
  __syncthreads();
  for (int s = 128; s; s >>= 1) {
    if (tid < s) part[tid] += part[tid + s];
    __syncthreads();
  }
  if (tid == 0) {
    const float invB = 1.0f / (float)B_ROWS;
    float mse = (red3[0] + red3[1] + red3[2] + red3[3]) * invB;
    float dd  = (red3[4] + red3[5] + red3[6] + red3[7]);
    float cc  = (red3[8] + red3[9] + red3[10] + red3[11]);
    float ce  = (cc - dd) * invB;
    float akld = 0.5f * part[0];
    out[0] = 0.5f * (mse + ce) + akld;
    out[1] = mse;
    out[2] = ce;
    out[3] = akld;
  }
}

extern "C" void kernel_launch(void* const* d_in, const int* in_sizes, int n_in,
                              void* d_out, int out_size, void* d_ws, size_t ws_size,
                              hipStream_t stream) {
  const float* enc = (const float*)d_in[0];   // data_encoded (B,12)
  const float* dec = (const float*)d_in[1];   // data_decoded (B,99)
  const float* tru = (const float*)d_in[2];   // data_true    (B,99)
  unsigned int* ws = (unsigned int*)d_ws;
  float* out = (float*)d_out;

  hipLaunchKernelGGL(k_minmax, dim3(128),         dim3(256), 0, stream, enc, ws);
  hipLaunchKernelGGL(k_hist,   dim3(128),         dim3(256), 0, stream, enc, ws);
  hipLaunchKernelGGL(k_main,   dim3(MAIN_BLOCKS), dim3(256), 0, stream, dec, tru, ws);
  hipLaunchKernelGGL(k_final,  dim3(1),           dim3(256), 0, stream, ws, out);
}